// Round 3
// baseline (453.379 us; speedup 1.0000x reference)
//
#include <hip/hip_runtime.h>
#include <hip/hip_bf16.h>

#define NN 64
#define CI 128
#define HD 128
#define KC 5
#define AJW 17    // byte-packed adj row stride in words (16 used + 1 pad)

// ws layout (floats): [0,1024) Wp B-fragments (4 frags x 64 lanes x 8 bf16)
//                     [1024,1152) y = W1 @ W2 @ Wl ; ws[1152] = b1.z ; ws[1153] = b2.Wl
#define WS_Y   1024
#define WS_B1Z 1152
#define WS_B2W 1153

typedef float v4f __attribute__((ext_vector_type(4)));
typedef __bf16 v8bf __attribute__((ext_vector_type(8)));
typedef unsigned short us8 __attribute__((ext_vector_type(8)));

__device__ __forceinline__ unsigned short f2us(float f) {
    __hip_bfloat16 h = __float2bfloat16(f);
    return *reinterpret_cast<unsigned short*>(&h);
}

// ---------------- pre-kernel: weights-only folding + B-fragment packing (1 block) ----------------
extern "C" __global__ void zprep(const float* __restrict__ W1,
                                 const float* __restrict__ Wp,
                                 const float* __restrict__ W2,
                                 const float* __restrict__ Wl,
                                 const float* __restrict__ b1,
                                 const float* __restrict__ b2,
                                 float* __restrict__ ws)
{
    const int t = threadIdx.x;   // 64 threads, single block
    __shared__ float sz_[HD];
    // z = W2 @ Wl
    float a0 = 0.f, a1 = 0.f;
    for (int c = 0; c < HD; ++c) {
        const float wl = Wl[c];
        a0 += W2[t * HD + c] * wl;
        a1 += W2[(t + 64) * HD + c] * wl;
    }
    sz_[t] = a0; sz_[t + 64] = a1;
    float p1 = b1[t] * a0 + b1[t + 64] * a1;
    float p2 = b2[t] * Wl[t] + b2[t + 64] * Wl[t + 64];
    #pragma unroll
    for (int off = 32; off; off >>= 1) {
        p1 += __shfl_down(p1, off, 64);
        p2 += __shfl_down(p2, off, 64);
    }
    if (t == 0) { ws[WS_B1Z] = p1; ws[WS_B2W] = p2; }
    __syncthreads();
    // y = W1 @ z
    #pragma unroll
    for (int rr = 0; rr < 2; ++rr) {
        const int r = t + rr * 64;
        float acc = 0.f;
        for (int h2 = 0; h2 < HD; ++h2) acc += W1[r * HD + h2] * sz_[h2];
        ws[WS_Y + r] = acc;
    }
    // Wp B-fragments: frag ks, lane t: n=t&15 (col), k=ks*32+(t>>4)*8+j
    const int q = t >> 4, m16 = t & 15;
    #pragma unroll
    for (int ks = 0; ks < 4; ++ks) {
        const int k0 = ks * 32 + q * 8;
        us8 pk;
        #pragma unroll
        for (int j = 0; j < 8; ++j)
            pk[j] = f2us((m16 < KC) ? Wp[(k0 + j) * KC + m16] : 0.f);
        reinterpret_cast<us8*>(ws)[ks * 64 + t] = pk;
    }
}

// ---------------- main kernel: one block per graph, 8 blocks/CU ----------------
extern "C" __global__ __launch_bounds__(256, 8)
void diffpool_main(const float* __restrict__ x,
                   const int* __restrict__ ei,
                   const float* __restrict__ bp,
                   const float* __restrict__ bl,
                   const float* __restrict__ ws,
                   float* __restrict__ out,
                   int E, int epg)
{
    __shared__ unsigned int sadjb[NN][AJW];  // byte-packed counts: 4 dst per word
    __shared__ float sA [4][NN * KC];        // s_pre partials
    __shared__ float sBu[4][NN * KC];        // U partials
    __shared__ float sc [4][NN];             // c = A_l(d*q) partials
    __shared__ float spp[4][25];             // adjp partials
    __shared__ float sSm[NN][KC];            // S0 (MFMA out) then softmaxed s (in place)
    __shared__ float sq[NN];                 // q[m] = x[m].y  (f32, fused into P1)
    __shared__ float sd[NN];                 // d = rsqrt(deg_l)
    __shared__ unsigned int srdeg[NN];       // raw row degree
    __shared__ float sz_[HD];                // y staged
    __shared__ float sadjp[25];
    __shared__ float sd2[KC];
    __shared__ float scoef[KC];

    const int t = threadIdx.x;
    const int g = blockIdx.x;
    const int lane = t & 63;
    const int wv = t >> 6;
    const int q4 = lane >> 4;
    const int m16 = lane & 15;
    const int n = lane;      // node owned in split stages
    const int h = wv;        // m-quarter owned in split stages
    const int arow = wv * 16 + m16;

    // uniform scalars (SGPR loads, issued early)
    const float bp0 = bp[0], bp1 = bp[1], bp2 = bp[2], bp3 = bp[3], bp4 = bp[4];
    const float c_b1z = ws[WS_B1Z], c_b2w = ws[WS_B2W], c_bl = bl[0];

    // edge prefetch (HBM latency hides under P0/B0)
    int e0s = -1, e0d = 0, e1s = -1, e1d = 0;
    const int base = g * epg;
    if (t < epg)       { e0s = ei[base + t] & 63;        e0d = ei[E + base + t] & 63; }
    if (t + 256 < epg) { e1s = ei[base + t + 256] & 63;  e1d = ei[E + base + t + 256] & 63; }

    // ---- P0: zero adj+deg; stage y ----
    {
        unsigned int* ap = &sadjb[0][0];
        for (int i = t; i < NN * AJW; i += 256) ap[i] = 0u;
        if (t < NN) srdeg[t] = 0u;
        if (t < 32)
            reinterpret_cast<float4*>(sz_)[t] = reinterpret_cast<const float4*>(ws + WS_Y)[t];
    }
    __syncthreads();   // B0

    // ---- P1: adjacency atomics + x->regs->MFMA S0 + fused f32 q ----
    {
        if (e0s >= 0) {
            atomicAdd(&sadjb[e0s][e0d >> 2], 1u << ((e0d & 3) * 8));
            atomicAdd(&srdeg[e0s], 1u);
        }
        if (e1s >= 0) {
            atomicAdd(&sadjb[e1s][e1d >> 2], 1u << ((e1d & 3) * 8));
            atomicAdd(&srdeg[e1s], 1u);
        }
        for (int j = t + 512; j < epg; j += 256) {   // generic tail
            const int sn = ei[base + j] & 63;
            const int dn = ei[E + base + j] & 63;
            atomicAdd(&sadjb[sn][dn >> 2], 1u << ((dn & 3) * 8));
            atomicAdd(&srdeg[sn], 1u);
        }
    }
    {
        // thread loads exactly its own MFMA A-fragments: row arow, cols ks*32+q4*8..+8
        const float* xr = x + (size_t)g * (NN * CI) + arow * CI;
        const v8bf* wpk = reinterpret_cast<const v8bf*>(ws);
        v4f acc = {0.f, 0.f, 0.f, 0.f};
        float qp = 0.f;
        #pragma unroll
        for (int ks = 0; ks < 4; ++ks) {
            const int c0 = ks * 32 + q4 * 8;
            const float4 v0 = *reinterpret_cast<const float4*>(xr + c0);
            const float4 v1 = *reinterpret_cast<const float4*>(xr + c0 + 4);
            const float4 y0 = *reinterpret_cast<const float4*>(sz_ + c0);
            const float4 y1 = *reinterpret_cast<const float4*>(sz_ + c0 + 4);
            qp += v0.x * y0.x + v0.y * y0.y + v0.z * y0.z + v0.w * y0.w
                + v1.x * y1.x + v1.y * y1.y + v1.z * y1.z + v1.w * y1.w;
            us8 pk;
            pk[0] = f2us(v0.x); pk[1] = f2us(v0.y); pk[2] = f2us(v0.z); pk[3] = f2us(v0.w);
            pk[4] = f2us(v1.x); pk[5] = f2us(v1.y); pk[6] = f2us(v1.z); pk[7] = f2us(v1.w);
            const v8bf af = *reinterpret_cast<const v8bf*>(&pk);
            acc = __builtin_amdgcn_mfma_f32_16x16x32_bf16(af, wpk[ks * 64 + lane], acc, 0, 0, 0);
        }
        // q: combine the 4 q4-lanes owning row arow
        qp += __shfl_xor(qp, 16, 64);
        qp += __shfl_xor(qp, 32, 64);
        if (q4 == 0) sq[arow] = qp;
        if (m16 < KC) {
            #pragma unroll
            for (int r = 0; r < 4; ++r)
                sSm[wv * 16 + q4 * 4 + r][m16] = acc[r];   // col=lane&15, row=q4*4+r
        }
    }
    __syncthreads();   // B1

    // ---- S1: d (redundant per wave); fused s_pre partials + c partials ----
    unsigned aw0, aw1, aw2, aw3;
    float dlane;
    {
        const unsigned selfb = (sadjb[lane][lane >> 2] >> ((lane & 3) * 8)) & 255u;
        dlane = rsqrtf((float)(srdeg[lane] + 1u - selfb));
        sd[lane] = dlane;            // redundant identical writes across waves: benign
        aw0 = sadjb[n][h * 4 + 0];
        aw1 = sadjb[n][h * 4 + 1];
        aw2 = sadjb[n][h * 4 + 2];
        aw3 = sadjb[n][h * 4 + 3];
        float a0 = 0.f, a1 = 0.f, a2 = 0.f, a3 = 0.f, a4 = 0.f, cp = 0.f;
        #pragma unroll
        for (int i = 0; i < 4; ++i) {
            const unsigned w = (i == 0) ? aw0 : (i == 1) ? aw1 : (i == 2) ? aw2 : aw3;
            #pragma unroll
            for (int bb = 0; bb < 4; ++bb) {
                const int m = h * 16 + i * 4 + bb;
                const float al = (m == n) ? 1.f : (float)((w >> (bb * 8)) & 255u);
                const float f = al * sd[m];      // same-wave write, broadcast read
                a0 += f * sSm[m][0]; a1 += f * sSm[m][1]; a2 += f * sSm[m][2];
                a3 += f * sSm[m][3]; a4 += f * sSm[m][4];
                cp += f * sq[m];                 // c[n] = sum_m adj_l[n][m]*d[m]*q[m]
            }
        }
        float* pp = &sA[h][n * KC];
        pp[0] = a0; pp[1] = a1; pp[2] = a2; pp[3] = a3; pp[4] = a4;
        sc[h][n] = cp;
    }
    __syncthreads();   // B2

    // ---- S2+S3 fused: all-wave redundant softmax (into sSm) then U partials ----
    float s0v, s1v, s2v, s3v, s4v;
    {
        float a0 = sA[0][n*KC+0] + sA[1][n*KC+0] + sA[2][n*KC+0] + sA[3][n*KC+0];
        float a1 = sA[0][n*KC+1] + sA[1][n*KC+1] + sA[2][n*KC+1] + sA[3][n*KC+1];
        float a2 = sA[0][n*KC+2] + sA[1][n*KC+2] + sA[2][n*KC+2] + sA[3][n*KC+2];
        float a3 = sA[0][n*KC+3] + sA[1][n*KC+3] + sA[2][n*KC+3] + sA[3][n*KC+3];
        float a4 = sA[0][n*KC+4] + sA[1][n*KC+4] + sA[2][n*KC+4] + sA[3][n*KC+4];
        a0 = a0 * dlane + bp0; a1 = a1 * dlane + bp1; a2 = a2 * dlane + bp2;
        a3 = a3 * dlane + bp3; a4 = a4 * dlane + bp4;
        const float mx = fmaxf(fmaxf(fmaxf(a0, a1), fmaxf(a2, a3)), a4);
        a0 = expf(a0 - mx); a1 = expf(a1 - mx); a2 = expf(a2 - mx);
        a3 = expf(a3 - mx); a4 = expf(a4 - mx);
        const float inv = 1.f / (a0 + a1 + a2 + a3 + a4);
        s0v = a0 * inv; s1v = a1 * inv; s2v = a2 * inv; s3v = a3 * inv; s4v = a4 * inv;
        sSm[n][0] = s0v; sSm[n][1] = s1v; sSm[n][2] = s2v;   // redundant identical writes
        sSm[n][3] = s3v; sSm[n][4] = s4v;
        // U = adj @ s partials (raw adj); sSm rows in this quarter written by this wave
        float u0 = 0.f, u1 = 0.f, u2 = 0.f, u3 = 0.f, u4 = 0.f;
        #pragma unroll
        for (int i = 0; i < 4; ++i) {
            const unsigned w = (i == 0) ? aw0 : (i == 1) ? aw1 : (i == 2) ? aw2 : aw3;
            #pragma unroll
            for (int bb = 0; bb < 4; ++bb) {
                const int m = h * 16 + i * 4 + bb;
                const float c = (float)((w >> (bb * 8)) & 255u);
                u0 += c * sSm[m][0]; u1 += c * sSm[m][1]; u2 += c * sSm[m][2];
                u3 += c * sSm[m][3]; u4 += c * sSm[m][4];
            }
        }
        float* pp = &sBu[h][n * KC];
        pp[0] = u0; pp[1] = u1; pp[2] = u2; pp[3] = u3; pp[4] = u4;
    }
    __syncthreads();   // B3

    // ---- S4: adjp = s^T U partials ----
    if (lane < 25) {
        const int k = lane / 5, l = lane - k * 5;
        float a = 0.f;
        #pragma unroll
        for (int i = 0; i < 16; ++i) {
            const int m = h * 16 + i;
            const float uu = sBu[0][m*KC+l] + sBu[1][m*KC+l]
                           + sBu[2][m*KC+l] + sBu[3][m*KC+l];
            a += sSm[m][k] * uu;
        }
        spp[h][lane] = a;
    }
    __syncthreads();   // B4

    // ---- S5: all-wave redundant scalar chain -> w -> out = w.c + cb*b1z + 5*b2wl + bl ----
    {
        if (lane < 25)
            sadjp[lane] = spp[0][lane] + spp[1][lane] + spp[2][lane] + spp[3][lane];
        if (lane < KC) {
            float s_ = 0.f;
            #pragma unroll
            for (int l = 0; l < KC; ++l) s_ += sadjp[lane * KC + l];
            s_ += 1.f - sadjp[lane * 6];
            sd2[lane] = rsqrtf(fmaxf(s_, 1.f));
        }
        if (lane < KC) {
            float a = 0.f;
            #pragma unroll
            for (int k = 0; k < KC; ++k) a += sd2[k] * sadjp[k * KC + lane];
            a += sd2[lane] * (1.f - sadjp[lane * 6]);
            scoef[lane] = sd2[lane] * a;
        }
        const float t5 = scoef[0] * s0v + scoef[1] * s1v + scoef[2] * s2v +
                         scoef[3] * s3v + scoef[4] * s4v;
        const float wn = dlane * t5;
        const float cfull = sc[0][n] + sc[1][n] + sc[2][n] + sc[3][n];
        float cb = t5;
        float v = wn * cfull;
        #pragma unroll
        for (int off = 32; off; off >>= 1) {
            cb += __shfl_down(cb, off, 64);
            v  += __shfl_down(v,  off, 64);
        }
        if (wv == 0 && lane == 0)
            out[g] = v + cb * c_b1z + 5.f * c_b2w + c_bl;
    }
}

extern "C" void kernel_launch(void* const* d_in, const int* in_sizes, int n_in,
                              void* d_out, int out_size, void* d_ws, size_t ws_size,
                              hipStream_t stream) {
    const float* x  = (const float*)d_in[0];
    const int*   ei = (const int*)d_in[1];
    // d_in[2] = batch (layout implied; unused)
    const float* Wp = (const float*)d_in[3];
    const float* bp = (const float*)d_in[4];
    const float* W1 = (const float*)d_in[5];
    const float* b1 = (const float*)d_in[6];
    const float* W2 = (const float*)d_in[7];
    const float* b2 = (const float*)d_in[8];
    const float* Wl = (const float*)d_in[9];
    const float* bl = (const float*)d_in[10];
    float* out = (float*)d_out;
    float* ws  = (float*)d_ws;

    const int B = out_size;            // 8192 graphs
    const int E = in_sizes[1] / 2;     // edge_index is [2, E]
    const int epg = E / B;             // 512 edges per graph

    zprep<<<1, 64, 0, stream>>>(W1, Wp, W2, Wl, b1, b2, ws);
    diffpool_main<<<B, 256, 0, stream>>>(x, ei, bp, bl, ws, out, E, epg);
}

// Round 5
// 425.641 us; speedup vs baseline: 1.0652x; 1.0652x over previous
//
#include <hip/hip_runtime.h>
#include <hip/hip_bf16.h>

#define NN 64
#define CI 128
#define HD 128
#define KC 5
#define AJW 17    // byte-packed adj row stride in words (16 used + 1 pad)

// ws layout (floats): [0,768) Wc[128][6] = [Wp | y] row-major; ws[768]=b1.z ; ws[769]=b2.Wl
#define WS_WC  0
#define WS_B1Z 768
#define WS_B2W 769

// ---------------- pre-kernel: weights-only folding (1 block, 64 threads) ----------------
extern "C" __global__ void zprep(const float* __restrict__ W1,
                                 const float* __restrict__ Wp,
                                 const float* __restrict__ W2,
                                 const float* __restrict__ Wl,
                                 const float* __restrict__ b1,
                                 const float* __restrict__ b2,
                                 float* __restrict__ ws)
{
    const int t = threadIdx.x;
    __shared__ float sz_[HD];
    // z = W2 @ Wl
    float a0 = 0.f, a1 = 0.f;
    for (int c = 0; c < HD; ++c) {
        const float wl = Wl[c];
        a0 += W2[t * HD + c] * wl;
        a1 += W2[(t + 64) * HD + c] * wl;
    }
    sz_[t] = a0; sz_[t + 64] = a1;
    float p1 = b1[t] * a0 + b1[t + 64] * a1;
    float p2 = b2[t] * Wl[t] + b2[t + 64] * Wl[t + 64];
    #pragma unroll
    for (int off = 32; off; off >>= 1) {
        p1 += __shfl_down(p1, off, 64);
        p2 += __shfl_down(p2, off, 64);
    }
    if (t == 0) { ws[WS_B1Z] = p1; ws[WS_B2W] = p2; }
    __syncthreads();
    // y = W1 @ z ; Wc[c][0..4] = Wp[c][*], Wc[c][5] = y[c]
    #pragma unroll
    for (int rr = 0; rr < 2; ++rr) {
        const int r = t + rr * 64;
        float acc = 0.f;
        for (int h2 = 0; h2 < HD; ++h2) acc += W1[r * HD + h2] * sz_[h2];
        #pragma unroll
        for (int k = 0; k < KC; ++k) ws[WS_WC + r * 6 + k] = Wp[r * KC + k];
        ws[WS_WC + r * 6 + 5] = acc;
    }
}

// ---------------- main kernel: one block per graph, 6 blocks/CU ----------------
extern "C" __global__ __launch_bounds__(256, 6)
void diffpool_main(const float* __restrict__ x,
                   const int* __restrict__ ei,
                   const float* __restrict__ bp,
                   const float* __restrict__ bl,
                   const float* __restrict__ ws,
                   float* __restrict__ out,
                   int E, int epg)
{
    __shared__ unsigned int sadjb[NN][AJW];  // byte-packed counts: 4 dst per word
    __shared__ float sA [4][NN * KC];        // s_pre partials
    __shared__ float sBu[4][NN * KC];        // U partials
    __shared__ float sc [4][NN];             // c = A_l(d*q) partials
    __shared__ float spp[4][25];             // adjp partials
    __shared__ float sSm[NN][6];             // S0 (f32) then softmaxed s (in place); pad 6
    __shared__ float sq[NN];                 // q[m] = x[m].y  (f32)
    __shared__ float sd[NN];                 // d = rsqrt(deg_l)
    __shared__ unsigned int srdeg[NN];       // raw row degree
    __shared__ float sadjp[25];
    __shared__ float sd2[KC];
    __shared__ float scoef[KC];

    const int t = threadIdx.x;
    const int g = blockIdx.x;
    const int lane = t & 63;
    const int wv = t >> 6;
    const int ch = t & 15;   // column chunk within a row (16 threads per row)
    const int n = lane;      // node owned in split stages
    const int h = wv;        // m-quarter owned in split stages

    // uniform scalars (SGPR loads, issued early)
    const float bp0 = bp[0], bp1 = bp[1], bp2 = bp[2], bp3 = bp[3], bp4 = bp[4];
    const float c_b1z = ws[WS_B1Z], c_b2w = ws[WS_B2W], c_bl = bl[0];

    // edge prefetch (HBM latency hides under P0)
    int e0s = -1, e0d = 0, e1s = -1, e1d = 0;
    const int base = g * epg;
    if (t < epg)       { e0s = ei[base + t] & 63;        e0d = ei[E + base + t] & 63; }
    if (t + 256 < epg) { e1s = ei[base + t + 256] & 63;  e1d = ei[E + base + t + 256] & 63; }

    // ---- P0: zero adj+deg ----
    {
        unsigned int* ap = &sadjb[0][0];
        for (int i = t; i < NN * AJW; i += 256) ap[i] = 0u;
        if (t < NN) srdeg[t] = 0u;
    }
    __syncthreads();   // B0

    // ---- P1: adjacency atomics (latency overlapped) + coalesced x loads
    //          fused into S0 = x@Wp and q = x.y (all f32) ----
    {
        if (e0s >= 0) {
            atomicAdd(&sadjb[e0s][e0d >> 2], 1u << ((e0d & 3) * 8));
            atomicAdd(&srdeg[e0s], 1u);
        }
        if (e1s >= 0) {
            atomicAdd(&sadjb[e1s][e1d >> 2], 1u << ((e1d & 3) * 8));
            atomicAdd(&srdeg[e1s], 1u);
        }
        for (int j = t + 512; j < epg; j += 256) {   // generic tail
            const int sn = ei[base + j] & 63;
            const int dn = ei[E + base + j] & 63;
            atomicAdd(&sadjb[sn][dn >> 2], 1u << ((dn & 3) * 8));
            atomicAdd(&srdeg[sn], 1u);
        }
        // per-thread Wc chunk: rows ch*8..+8, 6 cols = 48 floats (L2-hot; short live range)
        float wc[48];
        {
            const float4* wc4 = reinterpret_cast<const float4*>(ws + WS_WC + ch * 48);
            #pragma unroll
            for (int i4 = 0; i4 < 12; ++i4)
                *reinterpret_cast<float4*>(&wc[i4 * 4]) = wc4[i4];
        }
        const float* xg = x + (size_t)g * (NN * CI);
        #pragma unroll
        for (int i = 0; i < 4; ++i) {
            const int row = (t >> 4) + 16 * i;      // wave covers 4 rows = 2KB dense
            const float* xr = xg + row * CI + ch * 8;
            const float4 v0 = *reinterpret_cast<const float4*>(xr);
            const float4 v1 = *reinterpret_cast<const float4*>(xr + 4);
            float acc[6];
            #pragma unroll
            for (int k = 0; k < 6; ++k) acc[k] = 0.f;
            #pragma unroll
            for (int k = 0; k < 6; ++k) {
                acc[k] += v0.x * wc[0 * 6 + k] + v0.y * wc[1 * 6 + k]
                        + v0.z * wc[2 * 6 + k] + v0.w * wc[3 * 6 + k]
                        + v1.x * wc[4 * 6 + k] + v1.y * wc[5 * 6 + k]
                        + v1.z * wc[6 * 6 + k] + v1.w * wc[7 * 6 + k];
            }
            // butterfly over the 16 lanes sharing this row
            #pragma unroll
            for (int k = 0; k < 6; ++k) {
                float r = acc[k];
                r += __shfl_xor(r, 1, 16);
                r += __shfl_xor(r, 2, 16);
                r += __shfl_xor(r, 4, 16);
                r += __shfl_xor(r, 8, 16);
                acc[k] = r;
            }
            float val = acc[0];
            #pragma unroll
            for (int k = 1; k < 6; ++k) val = (ch == k) ? acc[k] : val;
            if (ch < KC)       sSm[row][ch] = val;
            else if (ch == 5)  sq[row] = val;
        }
    }
    __syncthreads();   // B1

    // ---- S1: d (redundant per wave); fused s_pre partials + c partials ----
    unsigned aw0, aw1, aw2, aw3;
    float dlane;
    {
        const unsigned selfb = (sadjb[lane][lane >> 2] >> ((lane & 3) * 8)) & 255u;
        dlane = rsqrtf((float)(srdeg[lane] + 1u - selfb));
        sd[lane] = dlane;            // redundant identical writes across waves: benign
        aw0 = sadjb[n][h * 4 + 0];
        aw1 = sadjb[n][h * 4 + 1];
        aw2 = sadjb[n][h * 4 + 2];
        aw3 = sadjb[n][h * 4 + 3];
        float a0 = 0.f, a1 = 0.f, a2 = 0.f, a3 = 0.f, a4 = 0.f, cp = 0.f;
        #pragma unroll
        for (int i = 0; i < 4; ++i) {
            const unsigned w = (i == 0) ? aw0 : (i == 1) ? aw1 : (i == 2) ? aw2 : aw3;
            #pragma unroll
            for (int bb = 0; bb < 4; ++bb) {
                const int m = h * 16 + i * 4 + bb;
                const float al = (m == n) ? 1.f : (float)((w >> (bb * 8)) & 255u);
                const float f = al * sd[m];      // same-wave write, broadcast read
                a0 += f * sSm[m][0]; a1 += f * sSm[m][1]; a2 += f * sSm[m][2];
                a3 += f * sSm[m][3]; a4 += f * sSm[m][4];
                cp += f * sq[m];                 // c[n] = sum_m adj_l[n][m]*d[m]*q[m]
            }
        }
        float* pp = &sA[h][n * KC];
        pp[0] = a0; pp[1] = a1; pp[2] = a2; pp[3] = a3; pp[4] = a4;
        sc[h][n] = cp;
    }
    __syncthreads();   // B2

    // ---- S2+S3 fused: all-wave redundant softmax (into sSm) then U partials ----
    float s0v, s1v, s2v, s3v, s4v;
    {
        float a0 = sA[0][n*KC+0] + sA[1][n*KC+0] + sA[2][n*KC+0] + sA[3][n*KC+0];
        float a1 = sA[0][n*KC+1] + sA[1][n*KC+1] + sA[2][n*KC+1] + sA[3][n*KC+1];
        float a2 = sA[0][n*KC+2] + sA[1][n*KC+2] + sA[2][n*KC+2] + sA[3][n*KC+2];
        float a3 = sA[0][n*KC+3] + sA[1][n*KC+3] + sA[2][n*KC+3] + sA[3][n*KC+3];
        float a4 = sA[0][n*KC+4] + sA[1][n*KC+4] + sA[2][n*KC+4] + sA[3][n*KC+4];
        a0 = a0 * dlane + bp0; a1 = a1 * dlane + bp1; a2 = a2 * dlane + bp2;
        a3 = a3 * dlane + bp3; a4 = a4 * dlane + bp4;
        const float mx = fmaxf(fmaxf(fmaxf(a0, a1), fmaxf(a2, a3)), a4);
        a0 = expf(a0 - mx); a1 = expf(a1 - mx); a2 = expf(a2 - mx);
        a3 = expf(a3 - mx); a4 = expf(a4 - mx);
        const float inv = 1.f / (a0 + a1 + a2 + a3 + a4);
        s0v = a0 * inv; s1v = a1 * inv; s2v = a2 * inv; s3v = a3 * inv; s4v = a4 * inv;
        sSm[n][0] = s0v; sSm[n][1] = s1v; sSm[n][2] = s2v;   // redundant identical writes
        sSm[n][3] = s3v; sSm[n][4] = s4v;
        // U = adj @ s partials (raw adj); sSm rows in this quarter written by this wave
        float u0 = 0.f, u1 = 0.f, u2 = 0.f, u3 = 0.f, u4 = 0.f;
        #pragma unroll
        for (int i = 0; i < 4; ++i) {
            const unsigned w = (i == 0) ? aw0 : (i == 1) ? aw1 : (i == 2) ? aw2 : aw3;
            #pragma unroll
            for (int bb = 0; bb < 4; ++bb) {
                const int m = h * 16 + i * 4 + bb;
                const float c = (float)((w >> (bb * 8)) & 255u);
                u0 += c * sSm[m][0]; u1 += c * sSm[m][1]; u2 += c * sSm[m][2];
                u3 += c * sSm[m][3]; u4 += c * sSm[m][4];
            }
        }
        float* pp = &sBu[h][n * KC];
        pp[0] = u0; pp[1] = u1; pp[2] = u2; pp[3] = u3; pp[4] = u4;
    }
    __syncthreads();   // B3

    // ---- S4: adjp = s^T U partials ----
    if (lane < 25) {
        const int k = lane / 5, l = lane - k * 5;
        float a = 0.f;
        #pragma unroll
        for (int i = 0; i < 16; ++i) {
            const int m = h * 16 + i;
            const float uu = sBu[0][m*KC+l] + sBu[1][m*KC+l]
                           + sBu[2][m*KC+l] + sBu[3][m*KC+l];
            a += sSm[m][k] * uu;
        }
        spp[h][lane] = a;
    }
    __syncthreads();   // B4

    // ---- S5: all-wave redundant scalar chain -> w -> out = w.c + cb*b1z + 5*b2wl + bl ----
    {
        if (lane < 25)
            sadjp[lane] = spp[0][lane] + spp[1][lane] + spp[2][lane] + spp[3][lane];
        if (lane < KC) {
            float s_ = 0.f;
            #pragma unroll
            for (int l = 0; l < KC; ++l) s_ += sadjp[lane * KC + l];
            s_ += 1.f - sadjp[lane * 6];
            sd2[lane] = rsqrtf(fmaxf(s_, 1.f));
        }
        if (lane < KC) {
            float a = 0.f;
            #pragma unroll
            for (int k = 0; k < KC; ++k) a += sd2[k] * sadjp[k * KC + lane];
            a += sd2[lane] * (1.f - sadjp[lane * 6]);
            scoef[lane] = sd2[lane] * a;
        }
        const float t5 = scoef[0] * s0v + scoef[1] * s1v + scoef[2] * s2v +
                         scoef[3] * s3v + scoef[4] * s4v;
        const float wn = dlane * t5;
        const float cfull = sc[0][n] + sc[1][n] + sc[2][n] + sc[3][n];
        float cb = t5;
        float v = wn * cfull;
        #pragma unroll
        for (int off = 32; off; off >>= 1) {
            cb += __shfl_down(cb, off, 64);
            v  += __shfl_down(v,  off, 64);
        }
        if (wv == 0 && lane == 0)
            out[g] = v + cb * c_b1z + 5.f * c_b2w + c_bl;
    }
}

extern "C" void kernel_launch(void* const* d_in, const int* in_sizes, int n_in,
                              void* d_out, int out_size, void* d_ws, size_t ws_size,
                              hipStream_t stream) {
    const float* x  = (const float*)d_in[0];
    const int*   ei = (const int*)d_in[1];
    // d_in[2] = batch (layout implied; unused)
    const float* Wp = (const float*)d_in[3];
    const float* bp = (const float*)d_in[4];
    const float* W1 = (const float*)d_in[5];
    const float* b1 = (const float*)d_in[6];
    const float* W2 = (const float*)d_in[7];
    const float* b2 = (const float*)d_in[8];
    const float* Wl = (const float*)d_in[9];
    const float* bl = (const float*)d_in[10];
    float* out = (float*)d_out;
    float* ws  = (float*)d_ws;

    const int B = out_size;            // 8192 graphs
    const int E = in_sizes[1] / 2;     // edge_index is [2, E]
    const int epg = E / B;             // 512 edges per graph

    zprep<<<1, 64, 0, stream>>>(W1, Wp, W2, Wl, b1, b2, ws);
    diffpool_main<<<B, 256, 0, stream>>>(x, ei, bp, bl, ws, out, E, epg);
}